// Round 1
// baseline (685.191 us; speedup 1.0000x reference)
//
#include <hip/hip_runtime.h>
#include <hip/hip_fp16.h>

typedef _Float16 f16x8 __attribute__((ext_vector_type(8)));
typedef _Float16 f16x4 __attribute__((ext_vector_type(4)));
typedef float f32x4 __attribute__((ext_vector_type(4)));

#define BM 128
#define BN 128
#define BK 64

__device__ __forceinline__ void gload_lds16(const void* g, void* l) {
  __builtin_amdgcn_global_load_lds((__attribute__((address_space(1))) void*)(g),
                                   (__attribute__((address_space(3))) void*)(l),
                                   16, 0, 0);
}

// EPI: 0 = fp16 out + bias, row-major [M,N]
//      1 = fp16 out + bias, transposed store out[col*ldc + row] (ldc = M_total)
//      2 = f32 out, row-major
//      3 = f32 atomicAdd, row-major (K-split)
template <int EPI>
__global__ __launch_bounds__(256, 3) void gemm_nt(
    const _Float16* __restrict__ A, int lda,
    const _Float16* __restrict__ B, int ldb,
    void* __restrict__ out, int ldc,
    const float* __restrict__ bias, int kchunk) {
  __shared__ __align__(16) _Float16 As[BM * BK];
  __shared__ __align__(16) _Float16 Bs[BN * BK];
  const int tid = threadIdx.x;
  const int wave = tid >> 6, lane = tid & 63;
  const int l15 = lane & 15, lg = lane >> 4;
  const int bm = blockIdx.x, bn = blockIdx.y;
  const int koff = blockIdx.z * kchunk;
  const _Float16* Ag = A + (size_t)bm * BM * lda + koff;
  const _Float16* Bg = B + (size_t)bn * BN * ldb + koff;
  const int wr = (wave >> 1) * 64, wc = (wave & 1) * 64;

  f32x4 acc[4][4];
#pragma unroll
  for (int m = 0; m < 4; ++m)
#pragma unroll
    for (int n = 0; n < 4; ++n) {
      f32x4 z = {0.f, 0.f, 0.f, 0.f};
      acc[m][n] = z;
    }

  for (int kt = 0; kt < kchunk; kt += BK) {
    __syncthreads();  // previous tile fully consumed
#pragma unroll
    for (int j = 0; j < 4; ++j) {
      const int c = wave * 256 + j * 64 + lane;
      gload_lds16(Ag + (size_t)(c >> 3) * lda + ((c & 7) << 3) + kt,
                  &As[(wave * 256 + j * 64) * 8]);
    }
#pragma unroll
    for (int j = 0; j < 4; ++j) {
      const int c = wave * 256 + j * 64 + lane;
      gload_lds16(Bg + (size_t)(c >> 3) * ldb + ((c & 7) << 3) + kt,
                  &Bs[(wave * 256 + j * 64) * 8]);
    }
    __syncthreads();  // compiler drains vmcnt before barrier
#pragma unroll
    for (int ks = 0; ks < 2; ++ks) {
      f16x8 af[4], bf[4];
      const int kb = ks * 32 + lg * 8;
#pragma unroll
      for (int m = 0; m < 4; ++m)
        af[m] = *(const f16x8*)&As[(wr + m * 16 + l15) * BK + kb];
#pragma unroll
      for (int n = 0; n < 4; ++n)
        bf[n] = *(const f16x8*)&Bs[(wc + n * 16 + l15) * BK + kb];
#pragma unroll
      for (int m = 0; m < 4; ++m)
#pragma unroll
        for (int n = 0; n < 4; ++n)
          acc[m][n] = __builtin_amdgcn_mfma_f32_16x16x32_f16(af[m], bf[n],
                                                             acc[m][n], 0, 0, 0);
    }
  }

  // epilogue — C/D layout (m89-verified): col = lane&15, row = (lane>>4)*4 + reg
  const int grow0 = bm * BM + wr + lg * 4;
  const int gcol0 = bn * BN + wc + l15;
  if constexpr (EPI == 1) {
#pragma unroll
    for (int m = 0; m < 4; ++m)
#pragma unroll
      for (int n = 0; n < 4; ++n) {
        const int col = gcol0 + n * 16;
        const int row = grow0 + m * 16;
        const float b = bias[col];
        f16x4 h;
#pragma unroll
        for (int r = 0; r < 4; ++r) h[r] = (_Float16)(acc[m][n][r] + b);
        *(f16x4*)&((_Float16*)out)[(size_t)col * ldc + row] = h;
      }
  } else {
#pragma unroll
    for (int m = 0; m < 4; ++m)
#pragma unroll
      for (int n = 0; n < 4; ++n)
#pragma unroll
        for (int r = 0; r < 4; ++r) {
          const int row = grow0 + m * 16 + r;
          const int col = gcol0 + n * 16;
          const float v = acc[m][n][r];
          if constexpr (EPI == 0)
            ((_Float16*)out)[(size_t)row * ldc + col] = (_Float16)(v + bias[col]);
          else if constexpr (EPI == 2)
            ((float*)out)[(size_t)row * ldc + col] = v;
          else
            atomicAdd((float*)out + (size_t)row * ldc + col, v);
        }
  }
}

__global__ __launch_bounds__(256) void cvt_f32_f16(const float4* __restrict__ in,
                                                   f16x4* __restrict__ out, int n4) {
  int i = blockIdx.x * 256 + threadIdx.x;
  const int stride = gridDim.x * 256;
  for (; i < n4; i += stride) {
    const float4 v = in[i];
    f16x4 h;
    h[0] = (_Float16)v.x;
    h[1] = (_Float16)v.y;
    h[2] = (_Float16)v.z;
    h[3] = (_Float16)v.w;
    out[i] = h;
  }
}

// One block per row of S [*, 8192]: P = exp(s - rowmax) / rowsum, fp16.
__global__ __launch_bounds__(256) void softmax_row(const float* __restrict__ S,
                                                   _Float16* __restrict__ P) {
  const int row = blockIdx.x;
  const int t = threadIdx.x;
  const float* s = S + (size_t)row * 8192;
  float loc[32];
  float m = -1e30f;
#pragma unroll
  for (int j = 0; j < 32; ++j) {
    loc[j] = s[j * 256 + t];
    m = fmaxf(m, loc[j]);
  }
#pragma unroll
  for (int off = 32; off > 0; off >>= 1) m = fmaxf(m, __shfl_xor(m, off));
  __shared__ float red[8];
  const int wv = t >> 6;
  if ((t & 63) == 0) red[wv] = m;
  __syncthreads();
  m = fmaxf(fmaxf(red[0], red[1]), fmaxf(red[2], red[3]));
  float sum = 0.f;
#pragma unroll
  for (int j = 0; j < 32; ++j) {
    loc[j] = __expf(loc[j] - m);
    sum += loc[j];
  }
#pragma unroll
  for (int off = 32; off > 0; off >>= 1) sum += __shfl_xor(sum, off);
  if ((t & 63) == 0) red[4 + wv] = sum;
  __syncthreads();
  sum = red[4] + red[5] + red[6] + red[7];
  const float inv = 1.0f / sum;
  _Float16* p = P + (size_t)row * 8192;
#pragma unroll
  for (int j = 0; j < 32; ++j) p[j * 256 + t] = (_Float16)(loc[j] * inv);
}

extern "C" void kernel_launch(void* const* d_in, const int* in_sizes, int n_in,
                              void* d_out, int out_size, void* d_ws, size_t ws_size,
                              hipStream_t stream) {
  (void)in_sizes; (void)n_in; (void)out_size;
  const int NTOK = 8192, DIM = 1024;
  const float* x  = (const float*)d_in[0];
  const float* wk = (const float*)d_in[1];
  const float* bk = (const float*)d_in[2];
  const float* wq = (const float*)d_in[3];
  const float* bq = (const float*)d_in[4];
  const float* wv = (const float*)d_in[5];
  const float* bv = (const float*)d_in[6];

  char* wp = (char*)d_ws;
  size_t off = 0;
  auto alloc = [&](size_t bytes) {
    void* r = wp + off;
    off += (bytes + 255) & ~(size_t)255;
    return r;
  };
  _Float16* xh  = (_Float16*)alloc((size_t)NTOK * DIM * 2);
  _Float16* wqh = (_Float16*)alloc((size_t)DIM * DIM * 2);
  _Float16* wkh = (_Float16*)alloc((size_t)DIM * DIM * 2);
  _Float16* wvh = (_Float16*)alloc((size_t)DIM * DIM * 2);
  _Float16* Qh  = (_Float16*)alloc((size_t)NTOK * DIM * 2);
  _Float16* Kh  = (_Float16*)alloc((size_t)NTOK * DIM * 2);
  _Float16* VT  = (_Float16*)alloc((size_t)DIM * NTOK * 2);  // V transposed [DIM, NTOK]

  // Slab size for score/P scratch, adapted to ws_size (R=4096 -> ~274MB total).
  int R = 4096;
  while (R > 256 && off + (size_t)R * NTOK * 6 + 512 > ws_size) R >>= 1;
  float*    Sraw = (float*)alloc((size_t)R * NTOK * 4);
  _Float16* P    = (_Float16*)alloc((size_t)R * NTOK * 2);

  // f32 -> fp16 converts
  cvt_f32_f16<<<2048, 256, 0, stream>>>((const float4*)x,  (f16x4*)xh,  NTOK * DIM / 4);
  cvt_f32_f16<<<256, 256, 0, stream>>>((const float4*)wq, (f16x4*)wqh, DIM * DIM / 4);
  cvt_f32_f16<<<256, 256, 0, stream>>>((const float4*)wk, (f16x4*)wkh, DIM * DIM / 4);
  cvt_f32_f16<<<256, 256, 0, stream>>>((const float4*)wv, (f16x4*)wvh, DIM * DIM / 4);

  // projections: Q, K row-major fp16; V stored transposed so PV is NT as well
  gemm_nt<0><<<dim3(NTOK / BM, DIM / BN), 256, 0, stream>>>(xh, DIM, wqh, DIM, Qh, DIM, bq, DIM);
  gemm_nt<0><<<dim3(NTOK / BM, DIM / BN), 256, 0, stream>>>(xh, DIM, wkh, DIM, Kh, DIM, bk, DIM);
  gemm_nt<1><<<dim3(NTOK / BM, DIM / BN), 256, 0, stream>>>(xh, DIM, wvh, DIM, VT, NTOK, bv, DIM);

  const int KS = (R >= 4096) ? 1 : (4096 / R);  // K-split for PV when slab is small
  if (KS > 1) hipMemsetAsync(d_out, 0, (size_t)NTOK * DIM * 4, stream);

  for (int s0 = 0; s0 < NTOK; s0 += R) {
    // S = Q_slab @ K^T  (raw f32 scores)
    gemm_nt<2><<<dim3(R / BM, NTOK / BN), 256, 0, stream>>>(
        Qh + (size_t)s0 * DIM, DIM, Kh, DIM, Sraw, NTOK, nullptr, DIM);
    // row softmax -> normalized fp16 P
    softmax_row<<<R, 256, 0, stream>>>(Sraw, P);
    // O_slab = P @ V   (= P @ VT^T, NT)
    float* outp = (float*)d_out + (size_t)s0 * DIM;
    if (KS == 1)
      gemm_nt<2><<<dim3(R / BM, DIM / BN), 256, 0, stream>>>(
          P, NTOK, VT, NTOK, outp, DIM, nullptr, NTOK);
    else
      gemm_nt<3><<<dim3(R / BM, DIM / BN, KS), 256, 0, stream>>>(
          P, NTOK, VT, NTOK, outp, DIM, nullptr, NTOK / KS);
  }
}

// Round 2
// 492.136 us; speedup vs baseline: 1.3923x; 1.3923x over previous
//
#include <hip/hip_runtime.h>
#include <hip/hip_fp16.h>

typedef _Float16 f16x8 __attribute__((ext_vector_type(8)));
typedef _Float16 f16x4 __attribute__((ext_vector_type(4)));
typedef float f32x4 __attribute__((ext_vector_type(4)));

#define BM 128
#define BN 128
#define BK 64

__device__ __forceinline__ void gload_lds16(const void* g, void* l) {
  __builtin_amdgcn_global_load_lds((__attribute__((address_space(1))) void*)(g),
                                   (__attribute__((address_space(3))) void*)(l),
                                   16, 0, 0);
}

// EPI: 0 = fp16 out + bias, row-major [M,N]
//      1 = fp16 out + bias, transposed store out[col*ldc + row] (ldc = M_total)
//      2 = f32 out, row-major
//      5 = fp16 raw, row-major, output base shifted by blockIdx.z (K-split partials)
template <int EPI>
__global__ __launch_bounds__(256, 3) void gemm_nt(
    const _Float16* __restrict__ A, int lda,
    const _Float16* __restrict__ B, int ldb,
    void* __restrict__ out, int ldc,
    const float* __restrict__ bias, int kchunk) {
  __shared__ __align__(16) _Float16 As[BM * BK];
  __shared__ __align__(16) _Float16 Bs[BN * BK];
  const int tid = threadIdx.x;
  const int wave = tid >> 6, lane = tid & 63;
  const int l15 = lane & 15, lg = lane >> 4;
  const int bm = blockIdx.x, bn = blockIdx.y;
  const int koff = blockIdx.z * kchunk;
  const _Float16* Ag = A + (size_t)bm * BM * lda + koff;
  const _Float16* Bg = B + (size_t)bn * BN * ldb + koff;
  const int wr = (wave >> 1) * 64, wc = (wave & 1) * 64;

  f32x4 acc[4][4];
#pragma unroll
  for (int m = 0; m < 4; ++m)
#pragma unroll
    for (int n = 0; n < 4; ++n) {
      f32x4 z = {0.f, 0.f, 0.f, 0.f};
      acc[m][n] = z;
    }

  for (int kt = 0; kt < kchunk; kt += BK) {
    __syncthreads();  // previous tile fully consumed
#pragma unroll
    for (int j = 0; j < 4; ++j) {
      const int c = wave * 256 + j * 64 + lane;
      gload_lds16(Ag + (size_t)(c >> 3) * lda + ((c & 7) << 3) + kt,
                  &As[(wave * 256 + j * 64) * 8]);
    }
#pragma unroll
    for (int j = 0; j < 4; ++j) {
      const int c = wave * 256 + j * 64 + lane;
      gload_lds16(Bg + (size_t)(c >> 3) * ldb + ((c & 7) << 3) + kt,
                  &Bs[(wave * 256 + j * 64) * 8]);
    }
    __syncthreads();  // compiler drains vmcnt before barrier
#pragma unroll
    for (int ks = 0; ks < 2; ++ks) {
      f16x8 af[4], bf[4];
      const int kb = ks * 32 + lg * 8;
#pragma unroll
      for (int m = 0; m < 4; ++m)
        af[m] = *(const f16x8*)&As[(wr + m * 16 + l15) * BK + kb];
#pragma unroll
      for (int n = 0; n < 4; ++n)
        bf[n] = *(const f16x8*)&Bs[(wc + n * 16 + l15) * BK + kb];
#pragma unroll
      for (int m = 0; m < 4; ++m)
#pragma unroll
        for (int n = 0; n < 4; ++n)
          acc[m][n] = __builtin_amdgcn_mfma_f32_16x16x32_f16(af[m], bf[n],
                                                             acc[m][n], 0, 0, 0);
    }
  }

  // epilogue — C/D layout (m89-verified): col = lane&15, row = (lane>>4)*4 + reg
  const int grow0 = bm * BM + wr + lg * 4;
  const int gcol0 = bn * BN + wc + l15;
  if constexpr (EPI == 1) {
#pragma unroll
    for (int m = 0; m < 4; ++m)
#pragma unroll
      for (int n = 0; n < 4; ++n) {
        const int col = gcol0 + n * 16;
        const int row = grow0 + m * 16;
        const float b = bias[col];
        f16x4 h;
#pragma unroll
        for (int r = 0; r < 4; ++r) h[r] = (_Float16)(acc[m][n][r] + b);
        *(f16x4*)&((_Float16*)out)[(size_t)col * ldc + row] = h;
      }
  } else {
    _Float16* o16 = (_Float16*)out;
    if constexpr (EPI == 5)
      o16 += (size_t)blockIdx.z * gridDim.x * (size_t)BM * ldc;
#pragma unroll
    for (int m = 0; m < 4; ++m)
#pragma unroll
      for (int n = 0; n < 4; ++n)
#pragma unroll
        for (int r = 0; r < 4; ++r) {
          const int row = grow0 + m * 16 + r;
          const int col = gcol0 + n * 16;
          const float v = acc[m][n][r];
          if constexpr (EPI == 0)
            ((_Float16*)out)[(size_t)row * ldc + col] = (_Float16)(v + bias[col]);
          else if constexpr (EPI == 2)
            ((float*)out)[(size_t)row * ldc + col] = v;
          else
            o16[(size_t)row * ldc + col] = (_Float16)v;
        }
  }
}

__global__ __launch_bounds__(256) void cvt_f32_f16(const float4* __restrict__ in,
                                                   f16x4* __restrict__ out, int n4) {
  int i = blockIdx.x * 256 + threadIdx.x;
  const int stride = gridDim.x * 256;
  for (; i < n4; i += stride) {
    const float4 v = in[i];
    f16x4 h;
    h[0] = (_Float16)v.x;
    h[1] = (_Float16)v.y;
    h[2] = (_Float16)v.z;
    h[3] = (_Float16)v.w;
    out[i] = h;
  }
}

// One block per row of S [*, 8192]: in-place P = exp(s - rowmax)/rowsum as fp16,
// written into the first 16KB of the row's own 32KB (f32 row read fully first;
// the __syncthreads in the reductions orders all reads before any write).
__global__ __launch_bounds__(256) void softmax_row(float* __restrict__ S) {
  const int row = blockIdx.x;
  const int t = threadIdx.x;
  float4* s4 = (float4*)(S + (size_t)row * 8192);
  float4 loc[8];
  float m = -1e30f;
#pragma unroll
  for (int j = 0; j < 8; ++j) {
    loc[j] = s4[j * 256 + t];
    m = fmaxf(m, fmaxf(fmaxf(loc[j].x, loc[j].y), fmaxf(loc[j].z, loc[j].w)));
  }
#pragma unroll
  for (int off = 32; off > 0; off >>= 1) m = fmaxf(m, __shfl_xor(m, off));
  __shared__ float red[8];
  const int wv = t >> 6;
  if ((t & 63) == 0) red[wv] = m;
  __syncthreads();
  m = fmaxf(fmaxf(red[0], red[1]), fmaxf(red[2], red[3]));
  float sum = 0.f;
#pragma unroll
  for (int j = 0; j < 8; ++j) {
    loc[j].x = __expf(loc[j].x - m);
    loc[j].y = __expf(loc[j].y - m);
    loc[j].z = __expf(loc[j].z - m);
    loc[j].w = __expf(loc[j].w - m);
    sum += loc[j].x + loc[j].y + loc[j].z + loc[j].w;
  }
#pragma unroll
  for (int off = 32; off > 0; off >>= 1) sum += __shfl_xor(sum, off);
  if ((t & 63) == 0) red[4 + wv] = sum;
  __syncthreads();
  sum = red[4] + red[5] + red[6] + red[7];
  const float inv = 1.0f / sum;
  f16x4* p4 = (f16x4*)(S + (size_t)row * 8192);
#pragma unroll
  for (int j = 0; j < 8; ++j) {
    f16x4 h;
    h[0] = (_Float16)(loc[j].x * inv);
    h[1] = (_Float16)(loc[j].y * inv);
    h[2] = (_Float16)(loc[j].z * inv);
    h[3] = (_Float16)(loc[j].w * inv);
    p4[j * 256 + t] = h;
  }
}

// out[i] = sum over 4 fp16 partials, vectorized x8. n8 = n/8.
__global__ __launch_bounds__(256) void reduce_ks(const _Float16* __restrict__ part,
                                                 float* __restrict__ out, int n8) {
  int i = blockIdx.x * 256 + threadIdx.x;
  if (i >= n8) return;
  const f16x8* p = (const f16x8*)part;
  const size_t s8 = (size_t)n8;
  f16x8 a = p[i], b = p[i + s8], c = p[i + 2 * s8], d = p[i + 3 * s8];
  float4 o0, o1;
  o0.x = (float)a[0] + (float)b[0] + (float)c[0] + (float)d[0];
  o0.y = (float)a[1] + (float)b[1] + (float)c[1] + (float)d[1];
  o0.z = (float)a[2] + (float)b[2] + (float)c[2] + (float)d[2];
  o0.w = (float)a[3] + (float)b[3] + (float)c[3] + (float)d[3];
  o1.x = (float)a[4] + (float)b[4] + (float)c[4] + (float)d[4];
  o1.y = (float)a[5] + (float)b[5] + (float)c[5] + (float)d[5];
  o1.z = (float)a[6] + (float)b[6] + (float)c[6] + (float)d[6];
  o1.w = (float)a[7] + (float)b[7] + (float)c[7] + (float)d[7];
  ((float4*)out)[2 * i] = o0;
  ((float4*)out)[2 * i + 1] = o1;
}

extern "C" void kernel_launch(void* const* d_in, const int* in_sizes, int n_in,
                              void* d_out, int out_size, void* d_ws, size_t ws_size,
                              hipStream_t stream) {
  (void)in_sizes; (void)n_in; (void)out_size;
  const int NTOK = 8192, DIM = 1024;
  const int KS = 4;  // K-split factor for PV (write-once partials, no atomics)
  const float* x  = (const float*)d_in[0];
  const float* wk = (const float*)d_in[1];
  const float* bk = (const float*)d_in[2];
  const float* wq = (const float*)d_in[3];
  const float* bq = (const float*)d_in[4];
  const float* wv = (const float*)d_in[5];
  const float* bv = (const float*)d_in[6];

  char* wp = (char*)d_ws;
  size_t off = 0;
  auto alloc = [&](size_t bytes) {
    void* r = wp + off;
    off += (bytes + 255) & ~(size_t)255;
    return r;
  };
  _Float16* xh  = (_Float16*)alloc((size_t)NTOK * DIM * 2);
  _Float16* wqh = (_Float16*)alloc((size_t)DIM * DIM * 2);
  _Float16* wkh = (_Float16*)alloc((size_t)DIM * DIM * 2);
  _Float16* wvh = (_Float16*)alloc((size_t)DIM * DIM * 2);
  _Float16* Qh  = (_Float16*)alloc((size_t)NTOK * DIM * 2);
  _Float16* Kh  = (_Float16*)alloc((size_t)NTOK * DIM * 2);
  _Float16* VT  = (_Float16*)alloc((size_t)DIM * NTOK * 2);  // V transposed [DIM, NTOK]

  // Slab scratch: Sraw f32 (P written in-place fp16 into row's first half)
  // + fp16 K-split partials. R=2048 -> ~154MB total (known to fit).
  int R = 8192;
  while (R > 256 &&
         off + (size_t)R * NTOK * 4 + (size_t)KS * R * DIM * 2 + 512 > ws_size)
    R >>= 1;
  float*    Sraw = (float*)alloc((size_t)R * NTOK * 4);
  _Float16* part = (_Float16*)alloc((size_t)KS * R * DIM * 2);

  // f32 -> fp16 converts
  cvt_f32_f16<<<2048, 256, 0, stream>>>((const float4*)x,  (f16x4*)xh,  NTOK * DIM / 4);
  cvt_f32_f16<<<256, 256, 0, stream>>>((const float4*)wq, (f16x4*)wqh, DIM * DIM / 4);
  cvt_f32_f16<<<256, 256, 0, stream>>>((const float4*)wk, (f16x4*)wkh, DIM * DIM / 4);
  cvt_f32_f16<<<256, 256, 0, stream>>>((const float4*)wv, (f16x4*)wvh, DIM * DIM / 4);

  // projections: Q, K row-major fp16; V stored transposed so PV is NT as well
  gemm_nt<0><<<dim3(NTOK / BM, DIM / BN), 256, 0, stream>>>(xh, DIM, wqh, DIM, Qh, DIM, bq, DIM);
  gemm_nt<0><<<dim3(NTOK / BM, DIM / BN), 256, 0, stream>>>(xh, DIM, wkh, DIM, Kh, DIM, bk, DIM);
  gemm_nt<1><<<dim3(NTOK / BM, DIM / BN), 256, 0, stream>>>(xh, DIM, wvh, DIM, VT, NTOK, bv, DIM);

  for (int s0 = 0; s0 < NTOK; s0 += R) {
    // S = Q_slab @ K^T  (raw f32 scores)
    gemm_nt<2><<<dim3(R / BM, NTOK / BN), 256, 0, stream>>>(
        Qh + (size_t)s0 * DIM, DIM, Kh, DIM, Sraw, NTOK, nullptr, DIM);
    // row softmax -> fp16 P in-place (row stride becomes 2*NTOK fp16 elements)
    softmax_row<<<R, 256, 0, stream>>>(Sraw);
    // partial[z] = P @ V over K-chunk z (fp16, write-once)
    gemm_nt<5><<<dim3(R / BM, DIM / BN, KS), 256, 0, stream>>>(
        (const _Float16*)Sraw, 2 * NTOK, VT, NTOK, part, DIM, nullptr, NTOK / KS);
    // O_slab = sum_z partial[z]
    reduce_ks<<<R * DIM / 8 / 256, 256, 0, stream>>>(
        part, (float*)d_out + (size_t)s0 * DIM, R * DIM / 8);
  }
}